// Round 7
// baseline (249.849 us; speedup 1.0000x reference)
//
#include <hip/hip_runtime.h>
#include <stdint.h>

#define B_DIM 8
#define N_DIM 2048
#define F_DIM 128
#define LN_EPS 1e-5f

typedef __attribute__((ext_vector_type(8))) short short8;
typedef __attribute__((ext_vector_type(4))) float floatx4;

// full RNE fp32 -> bf16
__device__ __forceinline__ ushort f2bf(float f) {
    union { float f; uint32_t u; } c;
    c.f = f;
    uint32_t u = c.u;
    return (ushort)((u + 0x7FFFu + ((u >> 16) & 1u)) >> 16);
}

// fast round-half-up pack of two fp32 -> packed bf16x2
__device__ __forceinline__ uint32_t pk2bf(float a, float b) {
    union { float f; uint32_t u; } x, y;
    x.f = a; y.f = b;
    return ((x.u + 0x8000u) >> 16) | ((y.u + 0x8000u) & 0xFFFF0000u);
}

__device__ __forceinline__ short8 pack8(float4 lo, float4 hi) {
    union { uint32_t u[4]; short8 s; } r;
    r.u[0] = pk2bf(lo.x, lo.y);
    r.u[1] = pk2bf(lo.z, lo.w);
    r.u[2] = pk2bf(hi.x, hi.y);
    r.u[3] = pk2bf(hi.z, hi.w);
    return r.s;
}

__device__ __forceinline__ void load_lds16(const ushort* g, ushort* l) {
    __builtin_amdgcn_global_load_lds(
        (const __attribute__((address_space(1))) void*)g,
        (__attribute__((address_space(3))) void*)l,
        16, 0, 0);
}

// ---------------------------------------------------------------------------
// Kernel 1 (prep): Yt[b,d,k] = (X[b] @ W^T)^T in bf16.  (verbatim from the
// passing round-6 version; associativity A@X@W^T = A@(X@W^T).)
// ---------------------------------------------------------------------------
__global__ __launch_bounds__(256) void k_prep(const float* __restrict__ X,
                                              const float* __restrict__ W,
                                              ushort* __restrict__ Yt) {
    __shared__ __align__(16) ushort Xs[64 * 128];  // 16 KB
    const int t = threadIdx.x;
    const int lane = t & 63;
    const int w = t >> 6;
    const int q = lane >> 4;
    const int mr = lane & 15;

    const int b = blockIdx.x >> 5;         // 0..7
    const int k0 = (blockIdx.x & 31) * 64; // 0..1984

    const int r = t >> 2;            // 0..63
    const int f0 = (t & 3) * 32;     // 0,32,64,96
    const float* src = X + (((size_t)b * N_DIM) + k0 + r) * F_DIM + f0;
    float4 v[8];
#pragma unroll
    for (int p = 0; p < 8; ++p) v[p] = ((const float4*)src)[p];
#pragma unroll
    for (int c2 = 0; c2 < 4; ++c2) {
        int chunk = (f0 >> 3) + c2;
        *(short8*)(Xs + r * 128 + ((chunk ^ (r & 7)) * 8)) =
            pack8(v[2 * c2], v[2 * c2 + 1]);
    }
    __syncthreads();

    floatx4 acc[4][2];
#pragma unroll
    for (int i = 0; i < 4; ++i)
#pragma unroll
        for (int j = 0; j < 2; ++j) acc[i][j] = (floatx4){0.f, 0.f, 0.f, 0.f};

#pragma unroll
    for (int ks = 0; ks < 4; ++ks) {
        short8 af[4];
#pragma unroll
        for (int i = 0; i < 4; ++i) {
            int m = i * 16 + mr;
            af[i] = *(const short8*)(Xs + m * 128 + (((ks * 4 + q) ^ (m & 7)) * 8));
        }
#pragma unroll
        for (int j = 0; j < 2; ++j) {
            const float* wp = W + (w * 32 + j * 16 + mr) * F_DIM + ks * 32 + q * 8;
            short8 wb = pack8(((const float4*)wp)[0], ((const float4*)wp)[1]);
#pragma unroll
            for (int i = 0; i < 4; ++i)
                acc[i][j] = __builtin_amdgcn_mfma_f32_16x16x32_bf16(af[i], wb,
                                                                    acc[i][j], 0, 0, 0);
        }
    }

#pragma unroll
    for (int i = 0; i < 4; ++i)
#pragma unroll
        for (int j = 0; j < 2; ++j) {
            int d = w * 32 + j * 16 + mr;
            union { ushort s[4]; uint2 u; } o;
#pragma unroll
            for (int r2 = 0; r2 < 4; ++r2) o.s[r2] = f2bf(acc[i][j][r2]);
            *(uint2*)(Yt + (((size_t)b * F_DIM) + d) * N_DIM + k0 + i * 16 + q * 4) =
                o.u;
        }
}

// ---------------------------------------------------------------------------
// Kernel 2 (fused): P = A@Y + b, LN(128), ReLU — BARRIER-FREE K-loop.
//
// v7: every barrier-synced variant (v0/v2/v6) ran the same ~55-60 us vs a
// 21.8 us A-read floor -> the block-wide barrier cadence is the invariant
// suspect.  This version removes all K-loop cross-wave sync:
//  - A fragments: identical for all waves -> load straight from global into
//    regs (L1/L2 absorbs the 4x re-read; HBM unchanged), pack fp32->bf16.
//  - B: wave-PRIVATE LDS double-buffer (8 KB/buf/wave), staged by each
//    wave's own global_load_lds; same conflict-free XOR swizzle bytes as v6.
//  - Sync: none.  The fp32->bf16 pack's implicit vmcnt(0) wait is the only
//    self-clock (it also guarantees the wave's own glds landed).
// 8 fully de-phased waves/CU keep the HBM queue continuously busy.
// LDS 64 KB -> 2 blocks/CU.  Epilogue (LN crosses waves): 2 __syncthreads.
// ---------------------------------------------------------------------------
__global__ __launch_bounds__(256, 2) void k_fused(const float* __restrict__ A,
                                                  const ushort* __restrict__ Yt,
                                                  const float* __restrict__ bias,
                                                  const float* __restrict__ gamma,
                                                  const float* __restrict__ beta,
                                                  float* __restrict__ out) {
    __shared__ __align__(16) char smem[65536];   // 4 waves x 2 bufs x 8 KB
    float (*const Pt)[132] = (float(*)[132])smem;  // epilogue alias (16.9 KB)

    const int t = threadIdx.x;
    const int lane = t & 63;
    const int w = t >> 6;            // wave 0..3
    const int q = lane >> 4;         // 0..3
    const int mr = lane & 15;        // 0..15

    const int bid = blockIdx.x;
    const int bb = bid & 7;          // batch -> XCD affinity (L2 keeps Yt slice)
    const int m0 = (bid >> 3) * 32;  // M-tile origin

    const float* Ab = A + ((size_t)bb * N_DIM + m0) * N_DIM;
    const ushort* Yb = Yt + (size_t)bb * F_DIM * N_DIM;

    ushort* const Bs0 = (ushort*)(smem + w * 16384);         // [32][128] bf16
    ushort* const Bs1 = (ushort*)(smem + w * 16384 + 8192);

    // ---- B staging map (wave-private): 8 glds chunks per lane.
    // slot c = p*64+lane (contiguous per wave, as glds requires);
    // local row np = c>>4 (0..31), source chunk kc = (c&15) ^ (np&7).
    const ushort* b_src[8];
    int b_off[8];
#pragma unroll
    for (int p = 0; p < 8; ++p) {
        int c = p * 64 + lane;
        int np = c >> 4;
        int kc = (c & 15) ^ (np & 7);
        b_src[p] = Yb + (size_t)(w * 32 + np) * N_DIM + kc * 8;
        b_off[p] = c * 8;
    }

    // ---- A fragment base: frag (i,ks) = A[m0 + i*16 + mr][k0 + ks*32 + q*8 ..+8]
    const float* a_base = Ab + (size_t)mr * N_DIM + q * 8;

    floatx4 acc[2][2];
#pragma unroll
    for (int i = 0; i < 2; ++i)
#pragma unroll
        for (int j = 0; j < 2; ++j) acc[i][j] = (floatx4){0.f, 0.f, 0.f, 0.f};

    float4 F[16];          // fp32 A staging (one tile)
    short8 S0[8], S1[8];   // bf16 A fragment sets (double-buffered)

    auto stageB = [&](int k0, ushort* Bn) {
#pragma unroll
        for (int p = 0; p < 8; ++p) load_lds16(b_src[p] + k0, Bn + b_off[p]);
    };
    auto loadA = [&](int k0) {
#pragma unroll
        for (int i = 0; i < 2; ++i) {
            const float* bi = a_base + (size_t)i * 16 * N_DIM + k0;
#pragma unroll
            for (int ks = 0; ks < 4; ++ks) {
                F[i * 8 + ks * 2]     = ((const float4*)(bi + ks * 32))[0];
                F[i * 8 + ks * 2 + 1] = ((const float4*)(bi + ks * 32))[1];
            }
        }
    };
    auto packS = [&](short8* S) {   // S[f], f = i*4+ks  <- F[2f], F[2f+1]
#pragma unroll
        for (int f = 0; f < 8; ++f) S[f] = pack8(F[2 * f], F[2 * f + 1]);
    };
    auto compute = [&](const short8* S, const ushort* Bc) {
#pragma unroll
        for (int ks = 0; ks < 4; ++ks) {
#pragma unroll
            for (int j = 0; j < 2; ++j) {
                int n = j * 16 + mr;
                short8 bfr = *(const short8*)(Bc + n * 128 +
                                              (((ks * 4 + q) ^ (n & 7)) * 8));
                acc[0][j] = __builtin_amdgcn_mfma_f32_16x16x32_bf16(
                    S[ks], bfr, acc[0][j], 0, 0, 0);
                acc[1][j] = __builtin_amdgcn_mfma_f32_16x16x32_bf16(
                    S[4 + ks], bfr, acc[1][j], 0, 0, 0);
            }
        }
    };

    // ---- prologue: tile 0 staged+packed; tile 1 in flight ----
    stageB(0, Bs0);
    loadA(0);
    packS(S0);                               // implicit vmcnt wait: B(0)+A(0) done
    __builtin_amdgcn_sched_barrier(0);
    stageB(128, Bs1);
    loadA(128);

    // ---- main loop: 16 tiles, unroll x2, ZERO barriers ----
#pragma unroll 1
    for (int tt = 0; tt < 14; tt += 2) {
        compute(S0, Bs0);                    // B(t) in LDS, A(t) in S0
        packS(S1);                           // waits glds(t+1)+A(t+1) (vmcnt)
        __builtin_amdgcn_sched_barrier(0);   // keep stage AFTER the pack waits
        stageB(tt * 128 + 256, Bs0);         // overwrite: this wave done reading
        loadA(tt * 128 + 256);

        compute(S1, Bs1);
        packS(S0);
        __builtin_amdgcn_sched_barrier(0);
        stageB(tt * 128 + 384, Bs1);
        loadA(tt * 128 + 384);
    }
    // ---- tail: tiles 14, 15 ----
    compute(S0, Bs0);
    packS(S1);                               // waits glds(15)+A(15)
    compute(S1, Bs1);

    __syncthreads();  // first cross-wave sync: before Pt aliases B buffers

    // ---- bias add, scatter P (fp32) for row-major LN
    // D layout: col=lane&15-based, row=q*4+reg [m89]
#pragma unroll
    for (int j = 0; j < 2; ++j) {
        int col = w * 32 + j * 16 + mr;
        float bcol = bias[col];
#pragma unroll
        for (int r = 0; r < 4; ++r) {
            Pt[q * 4 + r][col] = acc[0][j][r] + bcol;
            Pt[16 + q * 4 + r][col] = acc[1][j][r] + bcol;
        }
    }
    __syncthreads();

    // ---- LayerNorm + ReLU: 8 lanes per row, 16 values each
    const int row = t >> 3;
    const int seg = t & 7;
    float v[16];
    float s = 0.f, s2 = 0.f;
#pragma unroll
    for (int u = 0; u < 16; ++u) {
        v[u] = Pt[row][seg * 16 + u];
        s += v[u];
        s2 += v[u] * v[u];
    }
    s += __shfl_xor(s, 1);  s2 += __shfl_xor(s2, 1);
    s += __shfl_xor(s, 2);  s2 += __shfl_xor(s2, 2);
    s += __shfl_xor(s, 4);  s2 += __shfl_xor(s2, 4);
    float mu = s * (1.0f / 128.0f);
    float var = s2 * (1.0f / 128.0f) - mu * mu;
    float rs = rsqrtf(var + LN_EPS);

    float4 o[4];
    float* of = (float*)o;
#pragma unroll
    for (int u = 0; u < 16; ++u) {
        int d = seg * 16 + u;
        float y = (v[u] - mu) * rs * gamma[d] + beta[d];
        of[u] = fmaxf(y, 0.0f);
    }
    float4* dst = (float4*)(out + ((size_t)bb * N_DIM + m0 + row) * F_DIM + seg * 16);
    dst[0] = o[0]; dst[1] = o[1]; dst[2] = o[2]; dst[3] = o[3];
}

// ---------------------------------------------------------------------------
extern "C" void kernel_launch(void* const* d_in, const int* in_sizes, int n_in,
                              void* d_out, int out_size, void* d_ws, size_t ws_size,
                              hipStream_t stream) {
    const float* A     = (const float*)d_in[0];
    const float* X     = (const float*)d_in[1];
    const float* W     = (const float*)d_in[2];
    const float* bias  = (const float*)d_in[3];
    const float* gamma = (const float*)d_in[4];
    const float* beta  = (const float*)d_in[5];
    float* out = (float*)d_out;

    ushort* Yt = (ushort*)d_ws;  // 4 MB bf16

    k_prep<<<dim3(256), 256, 0, stream>>>(X, W, Yt);
    k_fused<<<dim3(512), 256, 0, stream>>>(A, Yt, bias, gamma, beta, out);
}

// Round 8
// 221.714 us; speedup vs baseline: 1.1269x; 1.1269x over previous
//
#include <hip/hip_runtime.h>
#include <stdint.h>

#define B_DIM 8
#define N_DIM 2048
#define F_DIM 128
#define LN_EPS 1e-5f

typedef __attribute__((ext_vector_type(8))) short short8;
typedef __attribute__((ext_vector_type(4))) float floatx4;

// full RNE fp32 -> bf16
__device__ __forceinline__ ushort f2bf(float f) {
    union { float f; uint32_t u; } c;
    c.f = f;
    uint32_t u = c.u;
    return (ushort)((u + 0x7FFFu + ((u >> 16) & 1u)) >> 16);
}

// fast round-half-up pack of two fp32 -> packed bf16x2
__device__ __forceinline__ uint32_t pk2bf(float a, float b) {
    union { float f; uint32_t u; } x, y;
    x.f = a; y.f = b;
    return ((x.u + 0x8000u) >> 16) | ((y.u + 0x8000u) & 0xFFFF0000u);
}

__device__ __forceinline__ short8 pack8(float4 lo, float4 hi) {
    union { uint32_t u[4]; short8 s; } r;
    r.u[0] = pk2bf(lo.x, lo.y);
    r.u[1] = pk2bf(lo.z, lo.w);
    r.u[2] = pk2bf(hi.x, hi.y);
    r.u[3] = pk2bf(hi.z, hi.w);
    return r.s;
}

// ---------------------------------------------------------------------------
// Kernel 1 (prep): Yt[b,d,k] = (X[b] @ W^T)^T in bf16.  (verbatim from the
// passing round-6 version; associativity A@X@W^T = A@(X@W^T).)
// ---------------------------------------------------------------------------
__global__ __launch_bounds__(256) void k_prep(const float* __restrict__ X,
                                              const float* __restrict__ W,
                                              ushort* __restrict__ Yt) {
    __shared__ __align__(16) ushort Xs[64 * 128];  // 16 KB
    const int t = threadIdx.x;
    const int lane = t & 63;
    const int w = t >> 6;
    const int q = lane >> 4;
    const int mr = lane & 15;

    const int b = blockIdx.x >> 5;         // 0..7
    const int k0 = (blockIdx.x & 31) * 64; // 0..1984

    const int r = t >> 2;            // 0..63
    const int f0 = (t & 3) * 32;     // 0,32,64,96
    const float* src = X + (((size_t)b * N_DIM) + k0 + r) * F_DIM + f0;
    float4 v[8];
#pragma unroll
    for (int p = 0; p < 8; ++p) v[p] = ((const float4*)src)[p];
#pragma unroll
    for (int c2 = 0; c2 < 4; ++c2) {
        int chunk = (f0 >> 3) + c2;
        *(short8*)(Xs + r * 128 + ((chunk ^ (r & 7)) * 8)) =
            pack8(v[2 * c2], v[2 * c2 + 1]);
    }
    __syncthreads();

    floatx4 acc[4][2];
#pragma unroll
    for (int i = 0; i < 4; ++i)
#pragma unroll
        for (int j = 0; j < 2; ++j) acc[i][j] = (floatx4){0.f, 0.f, 0.f, 0.f};

#pragma unroll
    for (int ks = 0; ks < 4; ++ks) {
        short8 af[4];
#pragma unroll
        for (int i = 0; i < 4; ++i) {
            int m = i * 16 + mr;
            af[i] = *(const short8*)(Xs + m * 128 + (((ks * 4 + q) ^ (m & 7)) * 8));
        }
#pragma unroll
        for (int j = 0; j < 2; ++j) {
            const float* wp = W + (w * 32 + j * 16 + mr) * F_DIM + ks * 32 + q * 8;
            short8 wb = pack8(((const float4*)wp)[0], ((const float4*)wp)[1]);
#pragma unroll
            for (int i = 0; i < 4; ++i)
                acc[i][j] = __builtin_amdgcn_mfma_f32_16x16x32_bf16(af[i], wb,
                                                                    acc[i][j], 0, 0, 0);
        }
    }

#pragma unroll
    for (int i = 0; i < 4; ++i)
#pragma unroll
        for (int j = 0; j < 2; ++j) {
            int d = w * 32 + j * 16 + mr;
            union { ushort s[4]; uint2 u; } o;
#pragma unroll
            for (int r2 = 0; r2 < 4; ++r2) o.s[r2] = f2bf(acc[i][j][r2]);
            *(uint2*)(Yt + (((size_t)b * F_DIM) + d) * N_DIM + k0 + i * 16 + q * 4) =
                o.u;
        }
}

// ---------------------------------------------------------------------------
// Kernel 2 (fused): P = A@Y + b, LN(128), ReLU.
//
// v8: B DIRECT-TO-REGISTERS (no glds, no Bs LDS).  A B-fragment load is
// 64 lanes = 16 Yt rows x 64 B fully-consumed cache lines, L2-resident by
// XCD affinity -> plain global loads, double-buffered in regs (8 short8/set).
// As stays in LDS (cross-wave shared, proven XOR swizzle).  The per-tile
// barrier now waits lgkmcnt(0) ONLY -- no VMEM drain, so A(t+2)+B(t+2)
// (12 VMEM instr/wave = ~96 KB/CU) remain in flight across every barrier;
// register WAR deps self-clock the B sets.  Removes 8 glds + 8 ds_read per
// wave/tile and the drain-burst HBM cadence of v0/v2/v6.
// LDS 17 KB (As dbuf 16 KB; epilogue Pt aliases).
// ---------------------------------------------------------------------------
__global__ __launch_bounds__(256, 2) void k_fused(const float* __restrict__ A,
                                                  const ushort* __restrict__ Yt,
                                                  const float* __restrict__ bias,
                                                  const float* __restrict__ gamma,
                                                  const float* __restrict__ beta,
                                                  float* __restrict__ out) {
    __shared__ __align__(16) char smem[17408];
    ushort* const As0 = (ushort*)smem;             // 32x128 bf16 = 8 KB, buf0
    ushort* const As1 = (ushort*)(smem + 8192);    // buf1
    float (*const Pt)[132] = (float(*)[132])smem;  // epilogue alias (16.9 KB)

    const int t = threadIdx.x;
    const int lane = t & 63;
    const int w = t >> 6;            // wave 0..3
    const int q = lane >> 4;         // 0..3
    const int mr = lane & 15;        // 0..15

    const int bid = blockIdx.x;
    const int bb = bid & 7;          // batch -> XCD affinity (L2 keeps Yt slice)
    const int m0 = (bid >> 3) * 32;  // M-tile origin

    const float* Ab = A + ((size_t)bb * N_DIM + m0) * N_DIM;
    const ushort* Yb = Yt + (size_t)bb * F_DIM * N_DIM;

    // ---- A staging (v2-proven): thread t -> row t>>3, 16 fp32 at k=(t&7)*16
    const int arow = t >> 3;
    const int asw_ = arow & 7;
    const float* a_src = Ab + (size_t)arow * N_DIM + (t & 7) * 16;
    const int a_off0 = arow * 128 + ((((t & 7) * 2) ^ asw_) * 8);
    const int a_off1 = arow * 128 + ((((t & 7) * 2 + 1) ^ asw_) * 8);

    // ---- B fragment base: lane(q,mr), wave w reads Yt rows w*32+j*16+mr
    const ushort* b_base = Yb + (size_t)(w * 32 + mr) * N_DIM + q * 8;

    floatx4 acc[2][2];
#pragma unroll
    for (int i = 0; i < 2; ++i)
#pragma unroll
        for (int j = 0; j < 2; ++j) acc[i][j] = (floatx4){0.f, 0.f, 0.f, 0.f};

    float4 r0[4], r1[4];     // A fp32 staging, double-buffered
    short8 B0[8], B1[8];     // B fragments, double-buffered (j*4+ks)

    auto loadA = [&](int k0, float4* r) {
        const float4* ap = (const float4*)(a_src + k0);
        r[0] = ap[0]; r[1] = ap[1]; r[2] = ap[2]; r[3] = ap[3];
    };
    auto loadB = [&](int k0, short8* Bv) {
#pragma unroll
        for (int j = 0; j < 2; ++j)
#pragma unroll
            for (int ks = 0; ks < 4; ++ks)
                Bv[j * 4 + ks] = *(const short8*)(b_base + (size_t)j * 16 * N_DIM +
                                                  k0 + ks * 32);
    };
    auto packA = [&](const float4* r, ushort* An) {
        *(short8*)(An + a_off0) = pack8(r[0], r[1]);
        *(short8*)(An + a_off1) = pack8(r[2], r[3]);
    };
    auto compute = [&](const ushort* Ac, const short8* Bv) {
#pragma unroll
        for (int ks = 0; ks < 4; ++ks) {
            short8 af[2];
#pragma unroll
            for (int i = 0; i < 2; ++i) {
                int m = mr + i * 16;
                af[i] = *(const short8*)(Ac + m * 128 + (((ks * 4 + q) ^ (m & 7)) * 8));
            }
#pragma unroll
            for (int j = 0; j < 2; ++j) {
#pragma unroll
                for (int i = 0; i < 2; ++i)
                    acc[i][j] = __builtin_amdgcn_mfma_f32_16x16x32_bf16(
                        af[i], Bv[j * 4 + ks], acc[i][j], 0, 0, 0);
            }
        }
    };

    // ---- prologue: As0/B0 = tile 0; r1/B1 = tile 1 (left in flight) ----
    loadA(0, r0);
    loadB(0, B0);
    packA(r0, As0);          // implicit vmcnt waits r0 (oldest); B0 stays in flight
    loadA(128, r1);
    loadB(128, B1);
    asm volatile("s_waitcnt lgkmcnt(0)" ::: "memory");
    __builtin_amdgcn_s_barrier();

    // ---- main loop: tiles 0..11 (6 x 2); issues reach tile 13 ----
#pragma unroll 1
    for (int tt = 0; tt < 12; tt += 2) {
        // even: compute t (As0,B0); refill B0/r0 with t+2; land As1 = t+1
        compute(As0, B0);
        loadB(tt * 128 + 256, B0);     // WAR on B0 regs orders after last use
        loadA(tt * 128 + 256, r0);
        packA(r1, As1);                // waits r1 (tile t+1) only
        asm volatile("s_waitcnt lgkmcnt(0)" ::: "memory");
        __builtin_amdgcn_s_barrier();

        // odd: compute t+1 (As1,B1); refill B1/r1 with t+3; land As0 = t+2
        compute(As1, B1);
        loadB(tt * 128 + 384, B1);
        loadA(tt * 128 + 384, r1);
        packA(r0, As0);
        asm volatile("s_waitcnt lgkmcnt(0)" ::: "memory");
        __builtin_amdgcn_s_barrier();
    }

    // ---- peeled tail: tiles 12..15 (issues stop at 15) ----
    compute(As0, B0);                  // t=12
    loadB(14 * 128, B0);
    loadA(14 * 128, r0);
    packA(r1, As1);
    asm volatile("s_waitcnt lgkmcnt(0)" ::: "memory");
    __builtin_amdgcn_s_barrier();

    compute(As1, B1);                  // t=13
    loadB(15 * 128, B1);
    loadA(15 * 128, r1);
    packA(r0, As0);
    asm volatile("s_waitcnt lgkmcnt(0)" ::: "memory");
    __builtin_amdgcn_s_barrier();

    compute(As0, B0);                  // t=14
    packA(r1, As1);
    asm volatile("s_waitcnt lgkmcnt(0)" ::: "memory");
    __builtin_amdgcn_s_barrier();

    compute(As1, B1);                  // t=15
    __syncthreads();  // full drain before Pt aliases As buffers

    // ---- bias add, scatter P (fp32) for row-major LN
    // D layout: col=lane&15-based, row=q*4+reg [m89]
#pragma unroll
    for (int j = 0; j < 2; ++j) {
        int col = w * 32 + j * 16 + mr;
        float bcol = bias[col];
#pragma unroll
        for (int r = 0; r < 4; ++r) {
            Pt[q * 4 + r][col] = acc[0][j][r] + bcol;
            Pt[16 + q * 4 + r][col] = acc[1][j][r] + bcol;
        }
    }
    __syncthreads();

    // ---- LayerNorm + ReLU: 8 lanes per row, 16 values each
    const int row = t >> 3;
    const int seg = t & 7;
    float v[16];
    float s = 0.f, s2 = 0.f;
#pragma unroll
    for (int u = 0; u < 16; ++u) {
        v[u] = Pt[row][seg * 16 + u];
        s += v[u];
        s2 += v[u] * v[u];
    }
    s += __shfl_xor(s, 1);  s2 += __shfl_xor(s2, 1);
    s += __shfl_xor(s, 2);  s2 += __shfl_xor(s2, 2);
    s += __shfl_xor(s, 4);  s2 += __shfl_xor(s2, 4);
    float mu = s * (1.0f / 128.0f);
    float var = s2 * (1.0f / 128.0f) - mu * mu;
    float rs = rsqrtf(var + LN_EPS);

    float4 o[4];
    float* of = (float*)o;
#pragma unroll
    for (int u = 0; u < 16; ++u) {
        int d = seg * 16 + u;
        float y = (v[u] - mu) * rs * gamma[d] + beta[d];
        of[u] = fmaxf(y, 0.0f);
    }
    float4* dst = (float4*)(out + ((size_t)bb * N_DIM + m0 + row) * F_DIM + seg * 16);
    dst[0] = o[0]; dst[1] = o[1]; dst[2] = o[2]; dst[3] = o[3];
}

// ---------------------------------------------------------------------------
extern "C" void kernel_launch(void* const* d_in, const int* in_sizes, int n_in,
                              void* d_out, int out_size, void* d_ws, size_t ws_size,
                              hipStream_t stream) {
    const float* A     = (const float*)d_in[0];
    const float* X     = (const float*)d_in[1];
    const float* W     = (const float*)d_in[2];
    const float* bias  = (const float*)d_in[3];
    const float* gamma = (const float*)d_in[4];
    const float* beta  = (const float*)d_in[5];
    float* out = (float*)d_out;

    ushort* Yt = (ushort*)d_ws;  // 4 MB bf16

    k_prep<<<dim3(256), 256, 0, stream>>>(X, W, Yt);
    k_fused<<<dim3(512), 256, 0, stream>>>(A, Yt, bias, gamma, beta, out);
}